// Round 1
// baseline (214.420 us; speedup 1.0000x reference)
//
#include <hip/hip_runtime.h>
#include <math.h>

#define N_STATES 32768
#define N_LABELS 64
#define N_BATCH  512

// Workspace float layout (all re-initialized every call; ws is poisoned 0xAA):
//   [0]           loss accumulator
//   [64 .. 575]   Z[512]   (softmax denominators, per batch col)
//   [576 .. 1087] M[512]   (stability offset: sum of positive f entries per b)
//   [1088 .. 1088+32767] U[64][512]  (unnormalized pMargin, label-major)
#define WS_LOSS 0
#define WS_Z    64
#define WS_M    576
#define WS_U    1088
#define WS_FLOATS (WS_U + N_LABELS * N_BATCH)  // 33856 floats = 135.4 KB

// ---------------------------------------------------------------------------
// Kernel 0: zero loss/Z/U, compute M[b] = sum_i max(f[b,i], 0).
// M_b is an upper bound on max_s potential[s,b] (potential is a subset sum of
// f[b,:], and any subset sum <= sum of positive entries), so exp(pot - M) <= 1
// and >= exp(-sum|f|) ~ exp(-51) -- safely inside fp32. Softmax is
// shift-invariant, so using a bound instead of the true max is exact.
__global__ void init_kernel(const float* __restrict__ f, float* __restrict__ ws) {
    int idx = blockIdx.x * 256 + threadIdx.x;
    if (idx >= WS_FLOATS) return;
    if (idx >= WS_M && idx < WS_M + N_BATCH) {
        int b = idx - WS_M;
        const float* fr = f + b * N_LABELS;
        float m = 0.f;
        #pragma unroll
        for (int i = 0; i < N_LABELS; i++) m += fmaxf(fr[i], 0.f);
        ws[idx] = m;
    } else {
        ws[idx] = 0.f;
    }
}

// ---------------------------------------------------------------------------
// Kernel 1: fused GEMM1 + exp + GEMM2 partial accumulation.
// Grid: 1024 blocks x 256 threads. blockIdx -> (btile in [0,8), chunk in [0,128)).
// Each wave: lane = batch column b = btile*64+lane; iterates 64 states.
// Per state: pot = dot64(S_row, f_row)  (f_row in registers),
//            E = exp(pot - M_b), Z += E, U[i] += E * S_row[i]  (U in registers).
// Partials merged with global fp32 atomics (contention: 512 adds/address).
__global__ __launch_bounds__(256) void
fused_kernel(const float* __restrict__ f, const float* __restrict__ S,
             float* __restrict__ ws) {
    float* Z = ws + WS_Z;
    const float* M = ws + WS_M;
    float* U = ws + WS_U;

    const int lane  = threadIdx.x & 63;
    const int w     = __builtin_amdgcn_readfirstlane(threadIdx.x >> 6);
    const int btile = blockIdx.x & 7;
    const int chunk = blockIdx.x >> 3;          // 0..127, 256 states each
    const int b     = btile * 64 + lane;

    // f row of this lane's batch column -> 64 registers
    float fr[N_LABELS];
    const float4* f4 = reinterpret_cast<const float4*>(f + (size_t)b * N_LABELS);
    #pragma unroll
    for (int k = 0; k < 16; k++) {
        float4 v = f4[k];
        fr[4*k+0] = v.x; fr[4*k+1] = v.y; fr[4*k+2] = v.z; fr[4*k+3] = v.w;
    }
    const float Mb = M[b];

    float Ureg[N_LABELS];
    #pragma unroll
    for (int i = 0; i < N_LABELS; i++) Ureg[i] = 0.f;
    float Zl = 0.f;

    const int s0 = chunk * 256 + w * 64;        // 64 states per wave
    for (int si = 0; si < 64; si++) {
        const int s = s0 + si;
        const float4* row4 = reinterpret_cast<const float4*>(S + (size_t)s * N_LABELS);
        float4 rv[16];
        #pragma unroll
        for (int k = 0; k < 16; k++) rv[k] = row4[k];   // wave-uniform address

        // dot64 with 4 independent accumulation chains
        float p0 = 0.f, p1 = 0.f, p2 = 0.f, p3 = 0.f;
        #pragma unroll
        for (int k = 0; k < 16; k++) {
            p0 = fmaf(rv[k].x, fr[4*k+0], p0);
            p1 = fmaf(rv[k].y, fr[4*k+1], p1);
            p2 = fmaf(rv[k].z, fr[4*k+2], p2);
            p3 = fmaf(rv[k].w, fr[4*k+3], p3);
        }
        const float pot = (p0 + p1) + (p2 + p3);
        const float E = __expf(pot - Mb);
        Zl += E;

        // scatter: U[i] += E * S[s][i]  (64 independent FMAs)
        #pragma unroll
        for (int k = 0; k < 16; k++) {
            Ureg[4*k+0] = fmaf(rv[k].x, E, Ureg[4*k+0]);
            Ureg[4*k+1] = fmaf(rv[k].y, E, Ureg[4*k+1]);
            Ureg[4*k+2] = fmaf(rv[k].z, E, Ureg[4*k+2]);
            Ureg[4*k+3] = fmaf(rv[k].w, E, Ureg[4*k+3]);
        }
    }

    atomicAdd(&Z[b], Zl);
    #pragma unroll
    for (int i = 0; i < N_LABELS; i++) {
        // U layout [label][batch] -> lanes (consecutive b) coalesce per i
        atomicAdd(&U[i * N_BATCH + b], Ureg[i]);
    }
}

// ---------------------------------------------------------------------------
// Kernel 2: pMargin = U/Z, clamp to [0,1], write d_out[1..], masked BCE with
// torch-style log clamp at -100, per-block reduce, atomicAdd into ws loss.
__global__ void finalize_kernel(const float* __restrict__ ws_ro,
                                float* __restrict__ ws,
                                const float* __restrict__ y,
                                const float* __restrict__ mask,
                                float* __restrict__ out) {
    const float* Z = ws_ro + WS_Z;
    const float* U = ws_ro + WS_U;

    int idx = blockIdx.x * 256 + threadIdx.x;   // 0..32767
    int b = idx >> 6;       // /64
    int i = idx & 63;

    float p = U[i * N_BATCH + b] / Z[b];
    p = fminf(fmaxf(p, 0.f), 1.f);
    out[1 + idx] = p;       // pMargin row-major [b][i]

    float lp  = fmaxf(logf(p), -100.f);         // logf(0) = -inf -> clamped
    float l1p = fmaxf(logf(1.f - p), -100.f);
    float yy = y[idx];
    float bce = -(yy * lp + (1.f - yy) * l1p) * mask[idx] * (1.f / (float)N_BATCH);

    // wave reduce (64-wide) then cross-wave via LDS, one atomic per block
    float v = bce;
    #pragma unroll
    for (int off = 32; off > 0; off >>= 1) v += __shfl_down(v, off, 64);
    __shared__ float wsum[4];
    if ((threadIdx.x & 63) == 0) wsum[threadIdx.x >> 6] = v;
    __syncthreads();
    if (threadIdx.x == 0)
        atomicAdd(&ws[WS_LOSS], wsum[0] + wsum[1] + wsum[2] + wsum[3]);
}

// Kernel 3: publish the loss scalar.
__global__ void write_loss_kernel(const float* __restrict__ ws, float* __restrict__ out) {
    if (threadIdx.x == 0 && blockIdx.x == 0) out[0] = ws[WS_LOSS];
}

// ---------------------------------------------------------------------------
extern "C" void kernel_launch(void* const* d_in, const int* in_sizes, int n_in,
                              void* d_out, int out_size, void* d_ws, size_t ws_size,
                              hipStream_t stream) {
    const float* f    = (const float*)d_in[0];   // [512, 64]
    const float* S    = (const float*)d_in[1];   // [32768, 64]
    const float* y    = (const float*)d_in[2];   // [512, 64]
    const float* mask = (const float*)d_in[3];   // [512, 64]
    float* out = (float*)d_out;                  // [1 + 512*64]
    float* ws  = (float*)d_ws;

    init_kernel<<<(WS_FLOATS + 255) / 256, 256, 0, stream>>>(f, ws);
    fused_kernel<<<1024, 256, 0, stream>>>(f, S, ws);
    finalize_kernel<<<(N_BATCH * N_LABELS) / 256, 256, 0, stream>>>(ws, ws, y, mask, out);
    write_loss_kernel<<<1, 64, 0, stream>>>(ws, out);
}

// Round 2
// 153.381 us; speedup vs baseline: 1.3980x; 1.3980x over previous
//
#include <hip/hip_runtime.h>
#include <math.h>

#define N_STATES 32768
#define N_LABELS 64
#define N_BATCH  512

// Workspace float layout (re-initialized every call; ws is poisoned 0xAA):
//   [64 .. 575]   Z[512]   (softmax denominators, per batch col)
//   [576 .. 1087] M[512]   (stability offset: sum of positive f entries per b)
//   [1088 ..]     U[64][512]  (unnormalized pMargin, label-major)
#define WS_Z    64
#define WS_M    576
#define WS_U    1088
#define WS_FLOATS (WS_U + N_LABELS * N_BATCH)  // 33856 floats

#define N_BLOCKS 512          // 8 btiles x 64 chunks; 512 states per block
#define STATES_PER_WAVE 128

// ---------------------------------------------------------------------------
// Kernel 0: zero Z/U and out[0], compute M[b] = sum_i max(f[b,i], 0).
// M_b bounds max_s potential[s,b] (potential is a subset sum of f[b,:]), so
// exp(pot - M) is in [~exp(-51), 1] -- safe fp32. Softmax is shift-invariant,
// so a bound instead of the true max is exact.
__global__ void init_kernel(const float* __restrict__ f, float* __restrict__ ws,
                            float* __restrict__ out) {
    int idx = blockIdx.x * 256 + threadIdx.x;
    if (idx == 0) out[0] = 0.f;                 // loss accumulator lives in out[0]
    if (idx >= WS_FLOATS) return;
    if (idx >= WS_M && idx < WS_M + N_BATCH) {
        int b = idx - WS_M;
        const float* fr = f + b * N_LABELS;
        float m = 0.f;
        #pragma unroll
        for (int i = 0; i < N_LABELS; i++) m += fmaxf(fr[i], 0.f);
        ws[idx] = m;
    } else {
        ws[idx] = 0.f;
    }
}

// ---------------------------------------------------------------------------
// Kernel 1: fused GEMM1 + exp + GEMM2 partial accumulation.
// Grid: 512 blocks x 256 threads; block = (btile in [0,8)) x (chunk in [0,64)).
// Lane = batch column b = btile*64+lane. Each wave handles 128 states,
// interleaved mod 4 across the block's 4 waves (scalar-cache reuse).
// Per state: pot = dot64(S_row, f_row) (f_row in regs, S_row via wave-uniform
// s_load), E = exp(pot - M_b), Z += E, Ureg[i] += E * S_row[i].
// launch_bounds(256,2): 256-VGPR budget so fr[64]+Ureg[64] do NOT spill
// (round 1: default budget 72 VGPRs -> scratch spill -> VALUBusy 20%).
// Cross-wave reduce through LDS, then ONE atomicAdd per (i,b) per block
// (2.1M atomic ops total vs 16.8M in round 1).
__global__ __launch_bounds__(256, 2) void
fused_kernel(const float* __restrict__ f, const float* __restrict__ S,
             float* __restrict__ ws) {
    __shared__ float red[4 * N_LABELS * 64];    // 64 KB

    float* Z = ws + WS_Z;
    const float* M = ws + WS_M;
    float* U = ws + WS_U;

    const int lane  = threadIdx.x & 63;
    const int w     = __builtin_amdgcn_readfirstlane(threadIdx.x >> 6);
    const int btile = blockIdx.x & 7;
    const int chunk = blockIdx.x >> 3;          // 0..63, 512 states each
    const int b     = btile * 64 + lane;

    // f row of this lane's batch column -> 64 registers
    float fr[N_LABELS];
    const float4* f4 = reinterpret_cast<const float4*>(f + (size_t)b * N_LABELS);
    #pragma unroll
    for (int k = 0; k < 16; k++) {
        float4 v = f4[k];
        fr[4*k+0] = v.x; fr[4*k+1] = v.y; fr[4*k+2] = v.z; fr[4*k+3] = v.w;
    }
    const float Mb = M[b];

    float Ureg[N_LABELS];
    #pragma unroll
    for (int i = 0; i < N_LABELS; i++) Ureg[i] = 0.f;
    float Zl = 0.f;

    const int s0 = chunk * 512 + w;             // stride-4 interleave across waves
    for (int si = 0; si < STATES_PER_WAVE; si++) {
        const int s = s0 + si * 4;
        const float4* row4 = reinterpret_cast<const float4*>(S + (size_t)s * N_LABELS);
        float4 rv[16];
        #pragma unroll
        for (int k = 0; k < 16; k++) rv[k] = row4[k];   // wave-uniform -> s_load

        float p0 = 0.f, p1 = 0.f, p2 = 0.f, p3 = 0.f;
        #pragma unroll
        for (int k = 0; k < 16; k++) {
            p0 = fmaf(rv[k].x, fr[4*k+0], p0);
            p1 = fmaf(rv[k].y, fr[4*k+1], p1);
            p2 = fmaf(rv[k].z, fr[4*k+2], p2);
            p3 = fmaf(rv[k].w, fr[4*k+3], p3);
        }
        const float pot = (p0 + p1) + (p2 + p3);
        const float E = __expf(pot - Mb);
        Zl += E;

        #pragma unroll
        for (int k = 0; k < 16; k++) {
            Ureg[4*k+0] = fmaf(rv[k].x, E, Ureg[4*k+0]);
            Ureg[4*k+1] = fmaf(rv[k].y, E, Ureg[4*k+1]);
            Ureg[4*k+2] = fmaf(rv[k].z, E, Ureg[4*k+2]);
            Ureg[4*k+3] = fmaf(rv[k].w, E, Ureg[4*k+3]);
        }
    }

    // --- cross-wave U reduction through LDS, one atomic per (i,b) per block ---
    #pragma unroll
    for (int i = 0; i < N_LABELS; i++)
        red[(w * N_LABELS + i) * 64 + lane] = Ureg[i];   // lanes consecutive: conflict-free
    __syncthreads();

    const int t = threadIdx.x;
    #pragma unroll
    for (int r = 0; r < 16; r++) {
        int idx = r * 256 + t;                  // consecutive t -> consecutive addr
        int i  = idx >> 6;
        int bb = idx & 63;
        float sum = red[(0 * N_LABELS + i) * 64 + bb]
                  + red[(1 * N_LABELS + i) * 64 + bb]
                  + red[(2 * N_LABELS + i) * 64 + bb]
                  + red[(3 * N_LABELS + i) * 64 + bb];
        atomicAdd(&U[i * N_BATCH + btile * 64 + bb], sum);
    }

    // --- cross-wave Z reduction ---
    __syncthreads();
    red[w * 64 + lane] = Zl;
    __syncthreads();
    if (w == 0) {
        float z = red[lane] + red[64 + lane] + red[128 + lane] + red[192 + lane];
        atomicAdd(&Z[b], z);
    }
}

// ---------------------------------------------------------------------------
// Kernel 2: pMargin = U/Z, clamp, write d_out[1..], masked BCE (log clamp
// -100), block-reduce, atomicAdd loss directly into out[0].
__global__ void finalize_kernel(const float* __restrict__ ws,
                                const float* __restrict__ y,
                                const float* __restrict__ mask,
                                float* __restrict__ out) {
    const float* Z = ws + WS_Z;
    const float* U = ws + WS_U;

    int idx = blockIdx.x * 256 + threadIdx.x;   // 0..32767
    int b = idx >> 6;
    int i = idx & 63;

    float p = U[i * N_BATCH + b] / Z[b];
    p = fminf(fmaxf(p, 0.f), 1.f);
    out[1 + idx] = p;                           // pMargin row-major [b][i]

    float lp  = fmaxf(logf(p), -100.f);
    float l1p = fmaxf(logf(1.f - p), -100.f);
    float yy = y[idx];
    float bce = -(yy * lp + (1.f - yy) * l1p) * mask[idx] * (1.f / (float)N_BATCH);

    float v = bce;
    #pragma unroll
    for (int off = 32; off > 0; off >>= 1) v += __shfl_down(v, off, 64);
    __shared__ float wsum[4];
    if ((threadIdx.x & 63) == 0) wsum[threadIdx.x >> 6] = v;
    __syncthreads();
    if (threadIdx.x == 0)
        atomicAdd(&out[0], wsum[0] + wsum[1] + wsum[2] + wsum[3]);
}

// ---------------------------------------------------------------------------
extern "C" void kernel_launch(void* const* d_in, const int* in_sizes, int n_in,
                              void* d_out, int out_size, void* d_ws, size_t ws_size,
                              hipStream_t stream) {
    const float* f    = (const float*)d_in[0];   // [512, 64]
    const float* S    = (const float*)d_in[1];   // [32768, 64]
    const float* y    = (const float*)d_in[2];   // [512, 64]
    const float* mask = (const float*)d_in[3];   // [512, 64]
    float* out = (float*)d_out;                  // [1 + 512*64]
    float* ws  = (float*)d_ws;

    init_kernel<<<(WS_FLOATS + 255) / 256, 256, 0, stream>>>(f, ws, out);
    fused_kernel<<<N_BLOCKS, 256, 0, stream>>>(f, S, ws);
    finalize_kernel<<<(N_BATCH * N_LABELS) / 256, 256, 0, stream>>>(ws, y, mask, out);
}

// Round 3
// 103.221 us; speedup vs baseline: 2.0773x; 1.4859x over previous
//
#include <hip/hip_runtime.h>
#include <hip/hip_bf16.h>
#include <math.h>

#define N_STATES 32768
#define N_LABELS 64
#define N_BATCH  512

// Workspace float layout (re-initialized every call; ws is poisoned 0xAA):
//   [64 .. 575]   Z[512]   (softmax denominators)
//   [576 .. 1087] M[512]   (stability offset: sum of positive f entries per b)
//   [1088 ..]     U[64][512]  (unnormalized pMargin, label-major)
#define WS_Z    64
#define WS_M    576
#define WS_U    1088
#define WS_FLOATS (WS_U + N_LABELS * N_BATCH)

#define LSTRIDE 72   // LDS row stride in bf16 elems: 64 + 8 pad (keeps every
                     // 8-consecutive-lane phase of ds_read_b128 conflict-free)

typedef __attribute__((ext_vector_type(8))) short  bfrag;   // 8 bf16 = 4 VGPRs
typedef __attribute__((ext_vector_type(4))) float  f32x4;

static __device__ __forceinline__ unsigned short f2bf(float x) {
    __hip_bfloat16 h = __float2bfloat16(x);
    return *reinterpret_cast<unsigned short*>(&h);
}
static __device__ __forceinline__ float bf2f(unsigned short u) {
    __hip_bfloat16 h;
    *reinterpret_cast<unsigned short*>(&h) = u;
    return __bfloat162float(h);
}

// ---------------------------------------------------------------------------
// Kernel 0: zero Z/U and out[0]; M[b] = sum_i max(f[b,i],0).
// M_b bounds max_s potential[s,b] (potential is a subset sum of f[b,:]), so
// exp(pot - M) in [~e^-51, 1]. Softmax is shift-invariant -> exact.
__global__ void init_kernel(const float* __restrict__ f, float* __restrict__ ws,
                            float* __restrict__ out) {
    int idx = blockIdx.x * 256 + threadIdx.x;
    if (idx == 0) out[0] = 0.f;
    if (idx >= WS_FLOATS) return;
    if (idx >= WS_M && idx < WS_M + N_BATCH) {
        int b = idx - WS_M;
        const float* fr = f + b * N_LABELS;
        float m = 0.f;
        #pragma unroll
        for (int i = 0; i < N_LABELS; i++) m += fmaxf(fr[i], 0.f);
        ws[idx] = m;
    } else {
        ws[idx] = 0.f;
    }
}

// ---------------------------------------------------------------------------
// Kernel 1: fused MFMA GEMM1 + exp + MFMA GEMM2.
// Grid: 512 blocks x 256 thr; block = (btile in [0,8)) x (chunk in [0,64)).
// Chunk = 512 states = 8 tiles of 64. Per tile:
//   stage:  S tile fp32->bf16 into S_t[s][k] and ST_t[k][s] (S is 0/1: exact)
//   GEMM1:  wave w computes pot[s=16w..+16][b=0..64] = S . f^T  (f as hi+lo
//           bf16 split -> ~fp32 accuracy), exp -> E hi/lo bf16 -> LDS E[b][s]
//   GEMM2:  wave w accumulates U[i=16w..+16][b=0..64] += S^T . E in 16
//           MFMA accumulators/lane (no big per-lane arrays -> no spill).
// Verified gfx950 16x16x32_bf16 layouts: C/D (m=quad*4+reg, n=lane&15);
// A lane holds A[m=lane&15][k=quad*8+j]; B lane holds B[k=quad*8+j][n=lane&15].
__global__ __launch_bounds__(256, 2) void
fused_kernel(const float* __restrict__ f, const float* __restrict__ S,
             float* __restrict__ ws) {
    __shared__ alignas(16) unsigned short f_hi[64 * LSTRIDE];
    __shared__ alignas(16) unsigned short f_lo[64 * LSTRIDE];
    __shared__ alignas(16) unsigned short S_t [64 * LSTRIDE];  // [s][k]
    __shared__ alignas(16) unsigned short ST_t[64 * LSTRIDE];  // [k][s]
    __shared__ alignas(16) unsigned short E_hi[64 * LSTRIDE];  // [b][s]
    __shared__ alignas(16) unsigned short E_lo[64 * LSTRIDE];  // [b][s]

    float* Z = ws + WS_Z;
    const float* M = ws + WS_M;
    float* U = ws + WS_U;

    const int t     = threadIdx.x;
    const int lane  = t & 63;
    const int w     = t >> 6;        // wave 0..3
    const int x     = lane & 15;
    const int quad  = lane >> 4;     // 0..3
    const int btile = blockIdx.x & 7;
    const int chunk = blockIdx.x >> 3;   // 0..63

    // ---- stage f tile once: [b_local][k], hi/lo bf16 split
    {
        const int row = t >> 2;      // 0..63 (b_local)
        const int q   = t & 3;       // 16 labels each
        const float4* p = reinterpret_cast<const float4*>(
            f + (size_t)(btile * 64 + row) * N_LABELS + q * 16);
        float4 v[4] = {p[0], p[1], p[2], p[3]};
        const float* vf = reinterpret_cast<const float*>(v);
        #pragma unroll
        for (int j = 0; j < 16; j++) {
            float val = vf[j];
            unsigned short h = f2bf(val);
            f_hi[row * LSTRIDE + q * 16 + j] = h;
            f_lo[row * LSTRIDE + q * 16 + j] = f2bf(val - bf2f(h));
        }
    }

    f32x4 Uacc[4];
    #pragma unroll
    for (int nt = 0; nt < 4; nt++) Uacc[nt] = (f32x4){0.f, 0.f, 0.f, 0.f};
    float zacc[4] = {0.f, 0.f, 0.f, 0.f};
    float Mv[4];
    #pragma unroll
    for (int nt = 0; nt < 4; nt++) Mv[nt] = M[btile * 64 + nt * 16 + x];

    const int sbase = chunk * 512;
    for (int st = 0; st < 8; st++) {
        const int s0 = sbase + st * 64;
        __syncthreads();   // previous GEMM2 done reading S_t/ST_t/E
        // ---- stage S tile (fp32 -> bf16, exact for 0/1), both layouts
        {
            const int row = t >> 2;   // state within tile
            const int q   = t & 3;
            const float4* p = reinterpret_cast<const float4*>(
                S + (size_t)(s0 + row) * N_LABELS + q * 16);
            float4 v[4] = {p[0], p[1], p[2], p[3]};
            const float* vf = reinterpret_cast<const float*>(v);
            #pragma unroll
            for (int j = 0; j < 16; j++) {
                unsigned short h = f2bf(vf[j]);
                S_t [row * LSTRIDE + q * 16 + j] = h;
                ST_t[(q * 16 + j) * LSTRIDE + row] = h;
            }
        }
        __syncthreads();

        // ---- GEMM1: pot[16w + (quad*4+reg)][nt*16 + x]
        bfrag a0 = *reinterpret_cast<const bfrag*>(&S_t[(16 * w + x) * LSTRIDE + quad * 8]);
        bfrag a1 = *reinterpret_cast<const bfrag*>(&S_t[(16 * w + x) * LSTRIDE + 32 + quad * 8]);
        #pragma unroll
        for (int nt = 0; nt < 4; nt++) {
            const int frow = (nt * 16 + x) * LSTRIDE + quad * 8;
            bfrag bh0 = *reinterpret_cast<const bfrag*>(&f_hi[frow]);
            bfrag bh1 = *reinterpret_cast<const bfrag*>(&f_hi[frow + 32]);
            bfrag bl0 = *reinterpret_cast<const bfrag*>(&f_lo[frow]);
            bfrag bl1 = *reinterpret_cast<const bfrag*>(&f_lo[frow + 32]);
            f32x4 acc = (f32x4){0.f, 0.f, 0.f, 0.f};
            acc = __builtin_amdgcn_mfma_f32_16x16x32_bf16(a0, bh0, acc, 0, 0, 0);
            acc = __builtin_amdgcn_mfma_f32_16x16x32_bf16(a1, bh1, acc, 0, 0, 0);
            acc = __builtin_amdgcn_mfma_f32_16x16x32_bf16(a0, bl0, acc, 0, 0, 0);
            acc = __builtin_amdgcn_mfma_f32_16x16x32_bf16(a1, bl1, acc, 0, 0, 0);

            // exp + hi/lo split, E stored transposed: E[b][s]
            ushort4 eh, el;
            float e0 = __expf(acc[0] - Mv[nt]);
            float e1 = __expf(acc[1] - Mv[nt]);
            float e2 = __expf(acc[2] - Mv[nt]);
            float e3 = __expf(acc[3] - Mv[nt]);
            zacc[nt] += (e0 + e1) + (e2 + e3);
            eh.x = f2bf(e0); el.x = f2bf(e0 - bf2f(eh.x));
            eh.y = f2bf(e1); el.y = f2bf(e1 - bf2f(eh.y));
            eh.z = f2bf(e2); el.z = f2bf(e2 - bf2f(eh.z));
            eh.w = f2bf(e3); el.w = f2bf(e3 - bf2f(eh.w));
            const int eoff = (nt * 16 + x) * LSTRIDE + 16 * w + quad * 4;
            *reinterpret_cast<ushort4*>(&E_hi[eoff]) = eh;
            *reinterpret_cast<ushort4*>(&E_lo[eoff]) = el;
        }
        __syncthreads();

        // ---- GEMM2: U[16w + (quad*4+reg)][nt*16 + x] += S^T . E
        bfrag c0 = *reinterpret_cast<const bfrag*>(&ST_t[(16 * w + x) * LSTRIDE + quad * 8]);
        bfrag c1 = *reinterpret_cast<const bfrag*>(&ST_t[(16 * w + x) * LSTRIDE + 32 + quad * 8]);
        #pragma unroll
        for (int nt = 0; nt < 4; nt++) {
            const int erow = (nt * 16 + x) * LSTRIDE + quad * 8;
            bfrag eh0 = *reinterpret_cast<const bfrag*>(&E_hi[erow]);
            bfrag eh1 = *reinterpret_cast<const bfrag*>(&E_hi[erow + 32]);
            bfrag el0 = *reinterpret_cast<const bfrag*>(&E_lo[erow]);
            bfrag el1 = *reinterpret_cast<const bfrag*>(&E_lo[erow + 32]);
            Uacc[nt] = __builtin_amdgcn_mfma_f32_16x16x32_bf16(c0, eh0, Uacc[nt], 0, 0, 0);
            Uacc[nt] = __builtin_amdgcn_mfma_f32_16x16x32_bf16(c1, eh1, Uacc[nt], 0, 0, 0);
            Uacc[nt] = __builtin_amdgcn_mfma_f32_16x16x32_bf16(c0, el0, Uacc[nt], 0, 0, 0);
            Uacc[nt] = __builtin_amdgcn_mfma_f32_16x16x32_bf16(c1, el1, Uacc[nt], 0, 0, 0);
        }
    }

    // ---- merge partials: U atomics (4096 distinct (i,b) per block)
    #pragma unroll
    for (int nt = 0; nt < 4; nt++) {
        #pragma unroll
        for (int r = 0; r < 4; r++) {
            int i = 16 * w + quad * 4 + r;
            int b = btile * 64 + nt * 16 + x;
            atomicAdd(&U[i * N_BATCH + b], Uacc[nt][r]);
        }
    }
    // ---- Z: quads hold disjoint s-partials for the same b -> shfl reduce
    #pragma unroll
    for (int nt = 0; nt < 4; nt++) {
        float v = zacc[nt];
        v += __shfl_down(v, 32, 64);
        v += __shfl_down(v, 16, 64);
        if (quad == 0)
            atomicAdd(&Z[btile * 64 + nt * 16 + x], v);
    }
}

// ---------------------------------------------------------------------------
// Kernel 2: pMargin = U/Z, clamp, write d_out[1..], masked BCE (log clamp
// -100), block-reduce, atomicAdd loss into out[0].
__global__ void finalize_kernel(const float* __restrict__ ws,
                                const float* __restrict__ y,
                                const float* __restrict__ mask,
                                float* __restrict__ out) {
    const float* Z = ws + WS_Z;
    const float* U = ws + WS_U;

    int idx = blockIdx.x * 256 + threadIdx.x;   // 0..32767
    int b = idx >> 6;
    int i = idx & 63;

    float p = U[i * N_BATCH + b] / Z[b];
    p = fminf(fmaxf(p, 0.f), 1.f);
    out[1 + idx] = p;                           // pMargin row-major [b][i]

    float lp  = fmaxf(logf(p), -100.f);
    float l1p = fmaxf(logf(1.f - p), -100.f);
    float yy = y[idx];
    float bce = -(yy * lp + (1.f - yy) * l1p) * mask[idx] * (1.f / (float)N_BATCH);

    float v = bce;
    #pragma unroll
    for (int off = 32; off > 0; off >>= 1) v += __shfl_down(v, off, 64);
    __shared__ float wsum[4];
    if ((threadIdx.x & 63) == 0) wsum[threadIdx.x >> 6] = v;
    __syncthreads();
    if (threadIdx.x == 0)
        atomicAdd(&out[0], wsum[0] + wsum[1] + wsum[2] + wsum[3]);
}

// ---------------------------------------------------------------------------
extern "C" void kernel_launch(void* const* d_in, const int* in_sizes, int n_in,
                              void* d_out, int out_size, void* d_ws, size_t ws_size,
                              hipStream_t stream) {
    const float* f    = (const float*)d_in[0];   // [512, 64]
    const float* S    = (const float*)d_in[1];   // [32768, 64]
    const float* y    = (const float*)d_in[2];   // [512, 64]
    const float* mask = (const float*)d_in[3];   // [512, 64]
    float* out = (float*)d_out;                  // [1 + 512*64]
    float* ws  = (float*)d_ws;

    init_kernel<<<(WS_FLOATS + 255) / 256, 256, 0, stream>>>(f, ws, out);
    fused_kernel<<<512, 256, 0, stream>>>(f, S, ws);
    finalize_kernel<<<(N_BATCH * N_LABELS) / 256, 256, 0, stream>>>(ws, y, mask, out);
}

// Round 4
// 103.065 us; speedup vs baseline: 2.0804x; 1.0015x over previous
//
#include <hip/hip_runtime.h>
#include <hip/hip_bf16.h>
#include <math.h>

#define N_STATES 32768
#define N_LABELS 64
#define N_BATCH  512

// ws float layout: Z[512]@64, M[512]@576, U[64*512]@1088
#define WS_Z    64
#define WS_M    576
#define WS_U    1088
// byte offsets for pre-materialized bf16 S (both layouts, bank-swizzled):
//   tile t (64 states): 8192 B; row r: 128 B; 8 chunks of 16 B; physical
//   chunk p = logical_chunk ^ (row & 7)  -> conflict-free ds_read_b128 AND
//   lane-contiguous rows for global_load_lds (swizzle baked into global).
#define SB_BYTE  262144u
#define STB_BYTE (SB_BYTE + 4194304u)

typedef __attribute__((ext_vector_type(8))) short          bfrag;
typedef __attribute__((ext_vector_type(4))) float          f32x4;
typedef __attribute__((ext_vector_type(8))) unsigned short u16x8;

static __device__ __forceinline__ unsigned short f2bf(float x) {
    __hip_bfloat16 h = __float2bfloat16(x);
    return *reinterpret_cast<unsigned short*>(&h);
}
static __device__ __forceinline__ float bf2f(unsigned short u) {
    __hip_bfloat16 h;
    *reinterpret_cast<unsigned short*>(&h) = u;
    return __bfloat162float(h);
}

typedef __attribute__((address_space(1))) const unsigned char g_u8;
typedef __attribute__((address_space(3))) unsigned char       l_u8;
static __device__ __forceinline__ void dma16(const void* g, void* l) {
    // async global->LDS, 16 B/lane; LDS dest = wave-uniform base + lane*16
    __builtin_amdgcn_global_load_lds((g_u8*)g, (l_u8*)l, 16, 0, 0);
}

// ---------------------------------------------------------------------------
// Prep: blocks 0..511 convert S tile -> Sb (natural) + STb (transposed), both
// bf16 + chunk-swizzled, and zero their U slice. Block 512: zero Z, out[0],
// compute M[b] = sum_i max(f[b,i],0)  (upper bound on max_s potential -> exp
// in [e^-51, 1]; softmax shift-invariance makes this exact).
__global__ __launch_bounds__(256) void prep_kernel(
    const float* __restrict__ f, const float* __restrict__ S,
    float* __restrict__ ws, float* __restrict__ out) {
    const int tb = blockIdx.x;
    const int t  = threadIdx.x;

    if (tb == 512) {                       // service block
        if (t == 0) out[0] = 0.f;
        for (int b = t; b < N_BATCH; b += 256) {
            ws[WS_Z + b] = 0.f;
            const float* fr = f + b * N_LABELS;
            float m = 0.f;
            #pragma unroll
            for (int i = 0; i < N_LABELS; i++) m += fmaxf(fr[i], 0.f);
            ws[WS_M + b] = m;
        }
        return;
    }

    if (t < 64) ws[WS_U + tb * 64 + t] = 0.f;

    __shared__ alignas(16) unsigned short Sl[64 * 72];   // natural bf16 tile

    unsigned short* SbW = (unsigned short*)((char*)ws + SB_BYTE);
    unsigned short* StW = (unsigned short*)((char*)ws + STB_BYTE);

    const int r = t >> 2;                  // state row within tile
    const int q = t & 3;                   // 16-label chunk
    const int m = r & 7;

    const float4* p4 = reinterpret_cast<const float4*>(
        S + ((size_t)(tb * 64 + r)) * N_LABELS + q * 16);
    float4 v0 = p4[0], v1 = p4[1], v2 = p4[2], v3 = p4[3];
    float vf[16] = {v0.x,v0.y,v0.z,v0.w, v1.x,v1.y,v1.z,v1.w,
                    v2.x,v2.y,v2.z,v2.w, v3.x,v3.y,v3.z,v3.w};
    u16x8 lo8, hi8;
    #pragma unroll
    for (int j = 0; j < 8; j++) { lo8[j] = f2bf(vf[j]); hi8[j] = f2bf(vf[8 + j]); }

    // natural LDS copy (for the transpose gather)
    *(u16x8*)&Sl[r * 72 + q * 16]     = lo8;
    *(u16x8*)&Sl[r * 72 + q * 16 + 8] = hi8;

    // swizzled Sb global write: logical chunks 2q,2q+1 -> 32B block at
    // chunk (2q)^(m&6); halves swapped when m odd.
    {
        unsigned short* dst = SbW + (size_t)tb * 4096 + r * 64 + (((2 * q) ^ (m & 6)) * 8);
        if (m & 1) { *(u16x8*)dst = hi8; *(u16x8*)(dst + 8) = lo8; }
        else       { *(u16x8*)dst = lo8; *(u16x8*)(dst + 8) = hi8; }
    }
    __syncthreads();

    // transpose gather: thread owns STb row i = r, states 16q..16q+15
    const int i  = r;
    const int mi = i & 7;
    u16x8 tlo, thi;
    #pragma unroll
    for (int j = 0; j < 8; j++) {
        tlo[j] = Sl[(16 * q + j)     * 72 + i];
        thi[j] = Sl[(16 * q + 8 + j) * 72 + i];
    }
    {
        unsigned short* dst = StW + (size_t)tb * 4096 + i * 64 + (((2 * q) ^ (mi & 6)) * 8);
        if (mi & 1) { *(u16x8*)dst = thi; *(u16x8*)(dst + 8) = tlo; }
        else        { *(u16x8*)dst = tlo; *(u16x8*)(dst + 8) = thi; }
    }
}

// ---------------------------------------------------------------------------
// Fused GEMM1 + exp + GEMM2. Grid 512 = 8 btiles x 64 chunks (8 tiles of 64
// states). DMA double-buffered staging of Sb/STb tiles; f-fragments (hi/lo
// bf16 split, ~fp32 accuracy) held in registers for the whole block; E single
// bf16. Raw s_barrier + hand vmcnt so the tile st+2 prefetch stays in flight.
__global__ __launch_bounds__(256, 2) void fused_kernel(
    const float* __restrict__ f, float* __restrict__ ws) {
    __shared__ alignas(16) unsigned short Sb2[2][4096];   // 16 KB
    __shared__ alignas(16) unsigned short St2[2][4096];   // 16 KB
    __shared__ alignas(16) unsigned short Et[64 * 72];    // 9.2 KB, E[b][s]

    float* Z = ws + WS_Z;
    const float* M = ws + WS_M;
    float* U = ws + WS_U;
    const char* SbG = (const char*)ws + SB_BYTE;
    const char* StG = (const char*)ws + STB_BYTE;

    const int t     = threadIdx.x;
    const int lane  = t & 63;
    const int w     = t >> 6;
    const int x     = lane & 15;
    const int quad  = lane >> 4;
    const int mm    = x & 7;
    const int btile = blockIdx.x & 7;
    const int chunk = blockIdx.x >> 3;
    const int tile0 = chunk * 8;

    // ---- f fragments in registers: B[k=i][n=b], hi/lo split
    bfrag fh[4][2], fl[4][2];
    #pragma unroll
    for (int nt = 0; nt < 4; nt++) {
        const float4* fp = reinterpret_cast<const float4*>(
            f + ((size_t)(btile * 64 + nt * 16 + x)) * N_LABELS);
        #pragma unroll
        for (int kh = 0; kh < 2; kh++) {
            float4 a = fp[kh * 8 + quad * 2];
            float4 b = fp[kh * 8 + quad * 2 + 1];
            float vv[8] = {a.x,a.y,a.z,a.w, b.x,b.y,b.z,b.w};
            #pragma unroll
            for (int j = 0; j < 8; j++) {
                unsigned short h = f2bf(vv[j]);
                fh[nt][kh][j] = (short)h;
                fl[nt][kh][j] = (short)f2bf(vv[j] - bf2f(h));
            }
        }
    }
    float Mv[4];
    #pragma unroll
    for (int nt = 0; nt < 4; nt++) Mv[nt] = M[btile * 64 + nt * 16 + x];

    f32x4 Uacc[4];
    #pragma unroll
    for (int nt = 0; nt < 4; nt++) Uacc[nt] = (f32x4){0.f, 0.f, 0.f, 0.f};
    float zacc[4] = {0.f, 0.f, 0.f, 0.f};

    auto stage = [&](int tile, int buf) {
        size_t gb = (size_t)tile * 8192 + (size_t)w * 2048 + (size_t)lane * 16;
        int lo = w * 2048;   // wave-uniform LDS byte offset
        dma16(SbG + gb,        (char*)&Sb2[buf][0] + lo);
        dma16(SbG + gb + 1024, (char*)&Sb2[buf][0] + lo + 1024);
        dma16(StG + gb,        (char*)&St2[buf][0] + lo);
        dma16(StG + gb + 1024, (char*)&St2[buf][0] + lo + 1024);
    };

    stage(tile0 + 0, 0);
    stage(tile0 + 1, 1);
    asm volatile("s_waitcnt vmcnt(4)" ::: "memory");   // tile0 landed
    asm volatile("s_barrier" ::: "memory");

    #pragma unroll
    for (int st = 0; st < 8; st++) {
        const int cur = st & 1;
        const unsigned short* Sb = &Sb2[cur][0];
        const unsigned short* St = &St2[cur][0];

        // ---- GEMM1: pot[s=16w+quad*4+r][b=nt*16+x], A row 16w+x swizzled
        bfrag a0 = *(const bfrag*)(Sb + (16 * w + x) * 64 + ((quad ^ mm) * 8));
        bfrag a1 = *(const bfrag*)(Sb + (16 * w + x) * 64 + (((quad + 4) ^ mm) * 8));
        #pragma unroll
        for (int nt = 0; nt < 4; nt++) {
            f32x4 acc = (f32x4){0.f, 0.f, 0.f, 0.f};
            acc = __builtin_amdgcn_mfma_f32_16x16x32_bf16(a0, fh[nt][0], acc, 0, 0, 0);
            acc = __builtin_amdgcn_mfma_f32_16x16x32_bf16(a1, fh[nt][1], acc, 0, 0, 0);
            acc = __builtin_amdgcn_mfma_f32_16x16x32_bf16(a0, fl[nt][0], acc, 0, 0, 0);
            acc = __builtin_amdgcn_mfma_f32_16x16x32_bf16(a1, fl[nt][1], acc, 0, 0, 0);
            float e0 = __expf(acc[0] - Mv[nt]);
            float e1 = __expf(acc[1] - Mv[nt]);
            float e2 = __expf(acc[2] - Mv[nt]);
            float e3 = __expf(acc[3] - Mv[nt]);
            zacc[nt] += (e0 + e1) + (e2 + e3);
            ushort4 ev;
            ev.x = f2bf(e0); ev.y = f2bf(e1); ev.z = f2bf(e2); ev.w = f2bf(e3);
            *(ushort4*)&Et[(nt * 16 + x) * 72 + 16 * w + quad * 4] = ev;
        }
        asm volatile("s_waitcnt lgkmcnt(0)" ::: "memory");  // E visible
        asm volatile("s_barrier" ::: "memory");

        // ---- GEMM2: U[i=16w+quad*4+r][b=nt*16+x] += S^T . E
        bfrag c0 = *(const bfrag*)(St + (16 * w + x) * 64 + ((quad ^ mm) * 8));
        bfrag c1 = *(const bfrag*)(St + (16 * w + x) * 64 + (((quad + 4) ^ mm) * 8));
        #pragma unroll
        for (int nt = 0; nt < 4; nt++) {
            bfrag e0 = *(const bfrag*)(Et + (nt * 16 + x) * 72 + quad * 8);
            bfrag e1 = *(const bfrag*)(Et + (nt * 16 + x) * 72 + 32 + quad * 8);
            Uacc[nt] = __builtin_amdgcn_mfma_f32_16x16x32_bf16(c0, e0, Uacc[nt], 0, 0, 0);
            Uacc[nt] = __builtin_amdgcn_mfma_f32_16x16x32_bf16(c1, e1, Uacc[nt], 0, 0, 0);
        }

        if (st < 6) {
            asm volatile("s_barrier" ::: "memory");          // cur fully consumed
            stage(tile0 + st + 2, cur);
            asm volatile("s_waitcnt vmcnt(4)" ::: "memory"); // tile st+1 landed
            asm volatile("s_barrier" ::: "memory");
        } else if (st == 6) {
            asm volatile("s_waitcnt vmcnt(0)" ::: "memory"); // tile 7 landed
            asm volatile("s_barrier" ::: "memory");
        }
    }

    // ---- merge partials (2.1M atomics total, known-OK level)
    #pragma unroll
    for (int nt = 0; nt < 4; nt++) {
        #pragma unroll
        for (int r = 0; r < 4; r++) {
            int i = 16 * w + quad * 4 + r;
            int b = btile * 64 + nt * 16 + x;
            atomicAdd(&U[i * N_BATCH + b], Uacc[nt][r]);
        }
    }
    #pragma unroll
    for (int nt = 0; nt < 4; nt++) {
        float v = zacc[nt];
        v += __shfl_down(v, 32, 64);
        v += __shfl_down(v, 16, 64);
        if (quad == 0) atomicAdd(&Z[btile * 64 + nt * 16 + x], v);
    }
}

// ---------------------------------------------------------------------------
// Finalize: pMargin = U/Z, clamp, write out[1..]; masked BCE (log clamp -100),
// block reduce, atomicAdd loss into out[0].
__global__ void finalize_kernel(const float* __restrict__ ws,
                                const float* __restrict__ y,
                                const float* __restrict__ mask,
                                float* __restrict__ out) {
    const float* Z = ws + WS_Z;
    const float* U = ws + WS_U;

    int idx = blockIdx.x * 256 + threadIdx.x;   // 0..32767
    int b = idx >> 6;
    int i = idx & 63;

    float p = U[i * N_BATCH + b] / Z[b];
    p = fminf(fmaxf(p, 0.f), 1.f);
    out[1 + idx] = p;

    float lp  = fmaxf(logf(p), -100.f);
    float l1p = fmaxf(logf(1.f - p), -100.f);
    float yy = y[idx];
    float bce = -(yy * lp + (1.f - yy) * l1p) * mask[idx] * (1.f / (float)N_BATCH);

    float v = bce;
    #pragma unroll
    for (int off = 32; off > 0; off >>= 1) v += __shfl_down(v, off, 64);
    __shared__ float wsum[4];
    if ((threadIdx.x & 63) == 0) wsum[threadIdx.x >> 6] = v;
    __syncthreads();
    if (threadIdx.x == 0)
        atomicAdd(&out[0], wsum[0] + wsum[1] + wsum[2] + wsum[3]);
}

// ---------------------------------------------------------------------------
extern "C" void kernel_launch(void* const* d_in, const int* in_sizes, int n_in,
                              void* d_out, int out_size, void* d_ws, size_t ws_size,
                              hipStream_t stream) {
    const float* f    = (const float*)d_in[0];   // [512, 64]
    const float* S    = (const float*)d_in[1];   // [32768, 64]
    const float* y    = (const float*)d_in[2];   // [512, 64]
    const float* mask = (const float*)d_in[3];   // [512, 64]
    float* out = (float*)d_out;                  // [1 + 512*64]
    float* ws  = (float*)d_ws;

    prep_kernel<<<513, 256, 0, stream>>>(f, S, ws, out);
    fused_kernel<<<512, 256, 0, stream>>>(f, ws);
    finalize_kernel<<<128, 256, 0, stream>>>(ws, y, mask, out);
}

// Round 5
// 102.296 us; speedup vs baseline: 2.0961x; 1.0075x over previous
//
#include <hip/hip_runtime.h>
#include <hip/hip_bf16.h>
#include <math.h>

#define N_STATES 32768
#define N_LABELS 64
#define N_BATCH  512

// ws float layout: Z[512]@64, M[512]@576, U[64*512]@1088
#define WS_Z    64
#define WS_M    576
#define WS_U    1088
// byte offsets for pre-materialized bf16 S (both layouts, bank-swizzled):
//   tile t (64 states): 8192 B; row r: 128 B; 8 chunks of 16 B; physical
//   chunk p = logical_chunk ^ (row & 7)  -> conflict-free ds_read_b128 AND
//   lane-contiguous rows for global_load_lds (swizzle baked into global).
#define SB_BYTE  262144u
#define STB_BYTE (SB_BYTE + 4194304u)

typedef __attribute__((ext_vector_type(8))) short          bfrag;
typedef __attribute__((ext_vector_type(4))) float          f32x4;
typedef __attribute__((ext_vector_type(8))) unsigned short u16x8;

static __device__ __forceinline__ unsigned short f2bf(float x) {
    __hip_bfloat16 h = __float2bfloat16(x);
    return *reinterpret_cast<unsigned short*>(&h);
}
static __device__ __forceinline__ float bf2f(unsigned short u) {
    __hip_bfloat16 h;
    *reinterpret_cast<unsigned short*>(&h) = u;
    return __bfloat162float(h);
}

typedef __attribute__((address_space(1))) const unsigned char g_u8;
typedef __attribute__((address_space(3))) unsigned char       l_u8;
static __device__ __forceinline__ void dma16(const void* g, void* l) {
    // async global->LDS, 16 B/lane; LDS dest = wave-uniform base + lane*16
    __builtin_amdgcn_global_load_lds((g_u8*)g, (l_u8*)l, 16, 0, 0);
}

// ---------------------------------------------------------------------------
// Prep: blocks 0..511 convert S tile -> Sb (natural) + STb (transposed), both
// bf16 + chunk-swizzled, and zero their U slice. Block 512: zero Z, out[0],
// compute M[b] = sum_i max(f[b,i],0)  (upper bound on max_s potential -> exp
// in [e^-51, 1]; softmax shift-invariance makes this exact).
__global__ __launch_bounds__(256) void prep_kernel(
    const float* __restrict__ f, const float* __restrict__ S,
    float* __restrict__ ws, float* __restrict__ out) {
    const int tb = blockIdx.x;
    const int t  = threadIdx.x;

    if (tb == 512) {                       // service block
        if (t == 0) out[0] = 0.f;
        for (int b = t; b < N_BATCH; b += 256) {
            ws[WS_Z + b] = 0.f;
            const float* fr = f + b * N_LABELS;
            float m = 0.f;
            #pragma unroll
            for (int i = 0; i < N_LABELS; i++) m += fmaxf(fr[i], 0.f);
            ws[WS_M + b] = m;
        }
        return;
    }

    if (t < 64) ws[WS_U + tb * 64 + t] = 0.f;

    __shared__ alignas(16) unsigned short Sl[64 * 72];   // natural bf16 tile

    unsigned short* SbW = (unsigned short*)((char*)ws + SB_BYTE);
    unsigned short* StW = (unsigned short*)((char*)ws + STB_BYTE);

    const int r = t >> 2;                  // state row within tile
    const int q = t & 3;                   // 16-label chunk
    const int m = r & 7;

    const float4* p4 = reinterpret_cast<const float4*>(
        S + ((size_t)(tb * 64 + r)) * N_LABELS + q * 16);
    float4 v0 = p4[0], v1 = p4[1], v2 = p4[2], v3 = p4[3];
    float vf[16] = {v0.x,v0.y,v0.z,v0.w, v1.x,v1.y,v1.z,v1.w,
                    v2.x,v2.y,v2.z,v2.w, v3.x,v3.y,v3.z,v3.w};
    u16x8 lo8, hi8;
    #pragma unroll
    for (int j = 0; j < 8; j++) { lo8[j] = f2bf(vf[j]); hi8[j] = f2bf(vf[8 + j]); }

    // natural LDS copy (for the transpose gather)
    *(u16x8*)&Sl[r * 72 + q * 16]     = lo8;
    *(u16x8*)&Sl[r * 72 + q * 16 + 8] = hi8;

    // swizzled Sb global write: logical chunks 2q,2q+1 -> 32B block at
    // chunk (2q)^(m&6); halves swapped when m odd.
    {
        unsigned short* dst = SbW + (size_t)tb * 4096 + r * 64 + (((2 * q) ^ (m & 6)) * 8);
        if (m & 1) { *(u16x8*)dst = hi8; *(u16x8*)(dst + 8) = lo8; }
        else       { *(u16x8*)dst = lo8; *(u16x8*)(dst + 8) = hi8; }
    }
    __syncthreads();

    // transpose gather: thread owns STb row i = r, states 16q..16q+15
    const int i  = r;
    const int mi = i & 7;
    u16x8 tlo, thi;
    #pragma unroll
    for (int j = 0; j < 8; j++) {
        tlo[j] = Sl[(16 * q + j)     * 72 + i];
        thi[j] = Sl[(16 * q + 8 + j) * 72 + i];
    }
    {
        unsigned short* dst = StW + (size_t)tb * 4096 + i * 64 + (((2 * q) ^ (mi & 6)) * 8);
        if (mi & 1) { *(u16x8*)dst = thi; *(u16x8*)(dst + 8) = tlo; }
        else        { *(u16x8*)dst = tlo; *(u16x8*)(dst + 8) = thi; }
    }
}

// ---------------------------------------------------------------------------
// Fused GEMM1 + exp + GEMM2. Grid 512 blocks.
// BLOCK MAPPING IS XCD-AFFINE: btile = blockIdx>>6, chunk = blockIdx&63.
// XCD round-robin (blockIdx % 8) then pins chunks c with c%8==j to XCD j for
// ALL btiles -> per-XCD Sb/STb working set = 8 chunks x 128 KB = 1 MB, fully
// L2-resident across the 8x re-read (round 4 mapping spread each chunk over
// all 8 XCDs -> 128 MB of LIC traffic, the observed ~40 us).
// DMA double-buffered staging; f-fragments (hi/lo bf16 split) in registers;
// E single bf16; raw s_barrier + hand vmcnt so prefetch stays in flight.
__global__ __launch_bounds__(256, 2) void fused_kernel(
    const float* __restrict__ f, float* __restrict__ ws) {
    __shared__ alignas(16) unsigned short Sb2[2][4096];   // 16 KB
    __shared__ alignas(16) unsigned short St2[2][4096];   // 16 KB
    __shared__ alignas(16) unsigned short Et[64 * 72];    // 9.2 KB, E[b][s]

    float* Z = ws + WS_Z;
    const float* M = ws + WS_M;
    float* U = ws + WS_U;
    const char* SbG = (const char*)ws + SB_BYTE;
    const char* StG = (const char*)ws + STB_BYTE;

    const int t     = threadIdx.x;
    const int lane  = t & 63;
    const int w     = t >> 6;
    const int x     = lane & 15;
    const int quad  = lane >> 4;
    const int mm    = x & 7;
    const int btile = blockIdx.x >> 6;   // XCD-affine: see header comment
    const int chunk = blockIdx.x & 63;
    const int tile0 = chunk * 8;

    // ---- f fragments in registers: B[k=i][n=b], hi/lo split
    bfrag fh[4][2], fl[4][2];
    #pragma unroll
    for (int nt = 0; nt < 4; nt++) {
        const float4* fp = reinterpret_cast<const float4*>(
            f + ((size_t)(btile * 64 + nt * 16 + x)) * N_LABELS);
        #pragma unroll
        for (int kh = 0; kh < 2; kh++) {
            float4 a = fp[kh * 8 + quad * 2];
            float4 b = fp[kh * 8 + quad * 2 + 1];
            float vv[8] = {a.x,a.y,a.z,a.w, b.x,b.y,b.z,b.w};
            #pragma unroll
            for (int j = 0; j < 8; j++) {
                unsigned short h = f2bf(vv[j]);
                fh[nt][kh][j] = (short)h;
                fl[nt][kh][j] = (short)f2bf(vv[j] - bf2f(h));
            }
        }
    }
    float Mv[4];
    #pragma unroll
    for (int nt = 0; nt < 4; nt++) Mv[nt] = M[btile * 64 + nt * 16 + x];

    f32x4 Uacc[4];
    #pragma unroll
    for (int nt = 0; nt < 4; nt++) Uacc[nt] = (f32x4){0.f, 0.f, 0.f, 0.f};
    float zacc[4] = {0.f, 0.f, 0.f, 0.f};

    auto stage = [&](int tile, int buf) {
        size_t gb = (size_t)tile * 8192 + (size_t)w * 2048 + (size_t)lane * 16;
        int lo = w * 2048;   // wave-uniform LDS byte offset
        dma16(SbG + gb,        (char*)&Sb2[buf][0] + lo);
        dma16(SbG + gb + 1024, (char*)&Sb2[buf][0] + lo + 1024);
        dma16(StG + gb,        (char*)&St2[buf][0] + lo);
        dma16(StG + gb + 1024, (char*)&St2[buf][0] + lo + 1024);
    };

    stage(tile0 + 0, 0);
    stage(tile0 + 1, 1);
    asm volatile("s_waitcnt vmcnt(4)" ::: "memory");   // tile0 landed
    asm volatile("s_barrier" ::: "memory");

    #pragma unroll
    for (int st = 0; st < 8; st++) {
        const int cur = st & 1;
        const unsigned short* Sb = &Sb2[cur][0];
        const unsigned short* St = &St2[cur][0];

        // ---- GEMM1: pot[s=16w+quad*4+r][b=nt*16+x], A row 16w+x swizzled
        bfrag a0 = *(const bfrag*)(Sb + (16 * w + x) * 64 + ((quad ^ mm) * 8));
        bfrag a1 = *(const bfrag*)(Sb + (16 * w + x) * 64 + (((quad + 4) ^ mm) * 8));
        #pragma unroll
        for (int nt = 0; nt < 4; nt++) {
            f32x4 acc = (f32x4){0.f, 0.f, 0.f, 0.f};
            acc = __builtin_amdgcn_mfma_f32_16x16x32_bf16(a0, fh[nt][0], acc, 0, 0, 0);
            acc = __builtin_amdgcn_mfma_f32_16x16x32_bf16(a1, fh[nt][1], acc, 0, 0, 0);
            acc = __builtin_amdgcn_mfma_f32_16x16x32_bf16(a0, fl[nt][0], acc, 0, 0, 0);
            acc = __builtin_amdgcn_mfma_f32_16x16x32_bf16(a1, fl[nt][1], acc, 0, 0, 0);
            float e0 = __expf(acc[0] - Mv[nt]);
            float e1 = __expf(acc[1] - Mv[nt]);
            float e2 = __expf(acc[2] - Mv[nt]);
            float e3 = __expf(acc[3] - Mv[nt]);
            zacc[nt] += (e0 + e1) + (e2 + e3);
            ushort4 ev;
            ev.x = f2bf(e0); ev.y = f2bf(e1); ev.z = f2bf(e2); ev.w = f2bf(e3);
            *(ushort4*)&Et[(nt * 16 + x) * 72 + 16 * w + quad * 4] = ev;
        }
        asm volatile("s_waitcnt lgkmcnt(0)" ::: "memory");  // E visible
        asm volatile("s_barrier" ::: "memory");

        // ---- GEMM2: U[i=16w+quad*4+r][b=nt*16+x] += S^T . E
        bfrag c0 = *(const bfrag*)(St + (16 * w + x) * 64 + ((quad ^ mm) * 8));
        bfrag c1 = *(const bfrag*)(St + (16 * w + x) * 64 + (((quad + 4) ^ mm) * 8));
        #pragma unroll
        for (int nt = 0; nt < 4; nt++) {
            bfrag e0 = *(const bfrag*)(Et + (nt * 16 + x) * 72 + quad * 8);
            bfrag e1 = *(const bfrag*)(Et + (nt * 16 + x) * 72 + 32 + quad * 8);
            Uacc[nt] = __builtin_amdgcn_mfma_f32_16x16x32_bf16(c0, e0, Uacc[nt], 0, 0, 0);
            Uacc[nt] = __builtin_amdgcn_mfma_f32_16x16x32_bf16(c1, e1, Uacc[nt], 0, 0, 0);
        }

        if (st < 6) {
            asm volatile("s_barrier" ::: "memory");          // cur fully consumed
            stage(tile0 + st + 2, cur);
            asm volatile("s_waitcnt vmcnt(4)" ::: "memory"); // tile st+1 landed
            asm volatile("s_barrier" ::: "memory");
        } else if (st == 6) {
            asm volatile("s_waitcnt vmcnt(0)" ::: "memory"); // tile 7 landed
            asm volatile("s_barrier" ::: "memory");
        }
    }

    // ---- merge partials (2.1M atomics total, known-OK level)
    #pragma unroll
    for (int nt = 0; nt < 4; nt++) {
        #pragma unroll
        for (int r = 0; r < 4; r++) {
            int i = 16 * w + quad * 4 + r;
            int b = btile * 64 + nt * 16 + x;
            atomicAdd(&U[i * N_BATCH + b], Uacc[nt][r]);
        }
    }
    #pragma unroll
    for (int nt = 0; nt < 4; nt++) {
        float v = zacc[nt];
        v += __shfl_down(v, 32, 64);
        v += __shfl_down(v, 16, 64);
        if (quad == 0) atomicAdd(&Z[btile * 64 + nt * 16 + x], v);
    }
}

// ---------------------------------------------------------------------------
// Finalize: pMargin = U/Z, clamp, write out[1..]; masked BCE (log clamp -100),
// block reduce, atomicAdd loss into out[0].
__global__ void finalize_kernel(const float* __restrict__ ws,
                                const float* __restrict__ y,
                                const float* __restrict__ mask,
                                float* __restrict__ out) {
    const float* Z = ws + WS_Z;
    const float* U = ws + WS_U;

    int idx = blockIdx.x * 256 + threadIdx.x;   // 0..32767
    int b = idx >> 6;
    int i = idx & 63;

    float p = U[i * N_BATCH + b] / Z[b];
    p = fminf(fmaxf(p, 0.f), 1.f);
    out[1 + idx] = p;

    float lp  = fmaxf(logf(p), -100.f);
    float l1p = fmaxf(logf(1.f - p), -100.f);
    float yy = y[idx];
    float bce = -(yy * lp + (1.f - yy) * l1p) * mask[idx] * (1.f / (float)N_BATCH);

    float v = bce;
    #pragma unroll
    for (int off = 32; off > 0; off >>= 1) v += __shfl_down(v, off, 64);
    __shared__ float wsum[4];
    if ((threadIdx.x & 63) == 0) wsum[threadIdx.x >> 6] = v;
    __syncthreads();
    if (threadIdx.x == 0)
        atomicAdd(&out[0], wsum[0] + wsum[1] + wsum[2] + wsum[3]);
}

// ---------------------------------------------------------------------------
extern "C" void kernel_launch(void* const* d_in, const int* in_sizes, int n_in,
                              void* d_out, int out_size, void* d_ws, size_t ws_size,
                              hipStream_t stream) {
    const float* f    = (const float*)d_in[0];   // [512, 64]
    const float* S    = (const float*)d_in[1];   // [32768, 64]
    const float* y    = (const float*)d_in[2];   // [512, 64]
    const float* mask = (const float*)d_in[3];   // [512, 64]
    float* out = (float*)d_out;                  // [1 + 512*64]
    float* ws  = (float*)d_ws;

    prep_kernel<<<513, 256, 0, stream>>>(f, S, ws, out);
    fused_kernel<<<512, 256, 0, stream>>>(f, ws);
    finalize_kernel<<<128, 256, 0, stream>>>(ws, y, mask, out);
}

// Round 6
// 96.550 us; speedup vs baseline: 2.2208x; 1.0595x over previous
//
#include <hip/hip_runtime.h>
#include <hip/hip_bf16.h>
#include <math.h>

#define N_STATES 32768
#define N_LABELS 64
#define N_BATCH  512

// ws layout:
//   floats: M[512] @ 0 ; Zp[8][64][64] @ ZP_F ; Up[8][64][64][64] @ UP_F
//   bytes : Sb (bf16, swizzled) @ SB_BYTE ; STb @ STB_BYTE
// Up/Zp are PER-BLOCK PRIVATE partials (btile,chunk) -> plain stores, no
// atomics, no zero-init (round 5 post-mortem: the 2.1M depth-64 atomic merge
// was the invariant ~25us tail across rounds 3-5).
#define WS_M_F   0
#define ZP_F     1024
#define UP_F     65536
#define SB_BYTE  8650752u
#define STB_BYTE 12845056u

typedef __attribute__((ext_vector_type(8))) short          bfrag;
typedef __attribute__((ext_vector_type(4))) float          f32x4;
typedef __attribute__((ext_vector_type(8))) unsigned short u16x8;

static __device__ __forceinline__ unsigned short f2bf(float x) {
    __hip_bfloat16 h = __float2bfloat16(x);
    return *reinterpret_cast<unsigned short*>(&h);
}
static __device__ __forceinline__ float bf2f(unsigned short u) {
    __hip_bfloat16 h;
    *reinterpret_cast<unsigned short*>(&h) = u;
    return __bfloat162float(h);
}

typedef __attribute__((address_space(1))) const unsigned char g_u8;
typedef __attribute__((address_space(3))) unsigned char       l_u8;
static __device__ __forceinline__ void dma16(const void* g, void* l) {
    __builtin_amdgcn_global_load_lds((g_u8*)g, (l_u8*)l, 16, 0, 0);
}

// ---------------------------------------------------------------------------
// Prep: blocks 0..511 convert S tile -> Sb (natural) + STb (transposed), bf16,
// chunk-swizzled (physical 16B chunk p = logical ^ (row&7) -> conflict-free
// ds_read_b128 AND verbatim global_load_lds rows). Block 512: M[b] =
// sum_i max(f[b,i],0) -- upper bound on max_s potential[s,b]; softmax
// shift-invariance makes the substitution exact, exp stays in [e^-51, 1].
__global__ __launch_bounds__(256) void prep_kernel(
    const float* __restrict__ f, const float* __restrict__ S,
    float* __restrict__ ws) {
    const int tb = blockIdx.x;
    const int t  = threadIdx.x;

    if (tb == 512) {                       // service block: M only
        for (int b = t; b < N_BATCH; b += 256) {
            const float* fr = f + b * N_LABELS;
            float m = 0.f;
            #pragma unroll
            for (int i = 0; i < N_LABELS; i++) m += fmaxf(fr[i], 0.f);
            ws[WS_M_F + b] = m;
        }
        return;
    }

    __shared__ alignas(16) unsigned short Sl[64 * 72];   // natural bf16 tile

    unsigned short* SbW = (unsigned short*)((char*)ws + SB_BYTE);
    unsigned short* StW = (unsigned short*)((char*)ws + STB_BYTE);

    const int r = t >> 2;                  // state row within tile
    const int q = t & 3;                   // 16-label chunk
    const int m = r & 7;

    const float4* p4 = reinterpret_cast<const float4*>(
        S + ((size_t)(tb * 64 + r)) * N_LABELS + q * 16);
    float4 v0 = p4[0], v1 = p4[1], v2 = p4[2], v3 = p4[3];
    float vf[16] = {v0.x,v0.y,v0.z,v0.w, v1.x,v1.y,v1.z,v1.w,
                    v2.x,v2.y,v2.z,v2.w, v3.x,v3.y,v3.z,v3.w};
    u16x8 lo8, hi8;
    #pragma unroll
    for (int j = 0; j < 8; j++) { lo8[j] = f2bf(vf[j]); hi8[j] = f2bf(vf[8 + j]); }

    *(u16x8*)&Sl[r * 72 + q * 16]     = lo8;
    *(u16x8*)&Sl[r * 72 + q * 16 + 8] = hi8;

    {
        unsigned short* dst = SbW + (size_t)tb * 4096 + r * 64 + (((2 * q) ^ (m & 6)) * 8);
        if (m & 1) { *(u16x8*)dst = hi8; *(u16x8*)(dst + 8) = lo8; }
        else       { *(u16x8*)dst = lo8; *(u16x8*)(dst + 8) = hi8; }
    }
    __syncthreads();

    const int i  = r;
    const int mi = i & 7;
    u16x8 tlo, thi;
    #pragma unroll
    for (int j = 0; j < 8; j++) {
        tlo[j] = Sl[(16 * q + j)     * 72 + i];
        thi[j] = Sl[(16 * q + 8 + j) * 72 + i];
    }
    {
        unsigned short* dst = StW + (size_t)tb * 4096 + i * 64 + (((2 * q) ^ (mi & 6)) * 8);
        if (mi & 1) { *(u16x8*)dst = thi; *(u16x8*)(dst + 8) = tlo; }
        else        { *(u16x8*)dst = tlo; *(u16x8*)(dst + 8) = thi; }
    }
}

// ---------------------------------------------------------------------------
// Fused GEMM1 + exp + GEMM2. Grid 512, XCD-affine (btile=blockIdx>>6,
// chunk=blockIdx&63 -> chunk c pinned to XCD c%8, per-XCD S working set 1 MB,
// L2-resident). DMA double-buffered Sb/STb staging; f-fragments (hi/lo bf16
// split ~ fp32 accuracy) in registers; E single bf16.
// Epilogue: PLAIN coalesced partial stores (no atomics) + out[0]=0.
__global__ __launch_bounds__(256, 2) void fused_kernel(
    const float* __restrict__ f, float* __restrict__ ws,
    float* __restrict__ out) {
    __shared__ alignas(16) unsigned short Sb2[2][4096];   // 16 KB
    __shared__ alignas(16) unsigned short St2[2][4096];   // 16 KB
    __shared__ alignas(16) unsigned short Et[64 * 72];    // 9.2 KB, E[b][s]

    const float* M = ws + WS_M_F;
    const char* SbG = (const char*)ws + SB_BYTE;
    const char* StG = (const char*)ws + STB_BYTE;

    const int t     = threadIdx.x;
    const int lane  = t & 63;
    const int w     = t >> 6;
    const int x     = lane & 15;
    const int quad  = lane >> 4;
    const int mm    = x & 7;
    const int btile = blockIdx.x >> 6;
    const int chunk = blockIdx.x & 63;
    const int tile0 = chunk * 8;

    bfrag fh[4][2], fl[4][2];
    #pragma unroll
    for (int nt = 0; nt < 4; nt++) {
        const float4* fp = reinterpret_cast<const float4*>(
            f + ((size_t)(btile * 64 + nt * 16 + x)) * N_LABELS);
        #pragma unroll
        for (int kh = 0; kh < 2; kh++) {
            float4 a = fp[kh * 8 + quad * 2];
            float4 b = fp[kh * 8 + quad * 2 + 1];
            float vv[8] = {a.x,a.y,a.z,a.w, b.x,b.y,b.z,b.w};
            #pragma unroll
            for (int j = 0; j < 8; j++) {
                unsigned short h = f2bf(vv[j]);
                fh[nt][kh][j] = (short)h;
                fl[nt][kh][j] = (short)f2bf(vv[j] - bf2f(h));
            }
        }
    }
    float Mv[4];
    #pragma unroll
    for (int nt = 0; nt < 4; nt++) Mv[nt] = M[btile * 64 + nt * 16 + x];

    f32x4 Uacc[4];
    #pragma unroll
    for (int nt = 0; nt < 4; nt++) Uacc[nt] = (f32x4){0.f, 0.f, 0.f, 0.f};
    float zacc[4] = {0.f, 0.f, 0.f, 0.f};

    auto stage = [&](int tile, int buf) {
        size_t gb = (size_t)tile * 8192 + (size_t)w * 2048 + (size_t)lane * 16;
        int lo = w * 2048;
        dma16(SbG + gb,        (char*)&Sb2[buf][0] + lo);
        dma16(SbG + gb + 1024, (char*)&Sb2[buf][0] + lo + 1024);
        dma16(StG + gb,        (char*)&St2[buf][0] + lo);
        dma16(StG + gb + 1024, (char*)&St2[buf][0] + lo + 1024);
    };

    stage(tile0 + 0, 0);
    stage(tile0 + 1, 1);
    asm volatile("s_waitcnt vmcnt(4)" ::: "memory");
    asm volatile("s_barrier" ::: "memory");

    #pragma unroll
    for (int st = 0; st < 8; st++) {
        const int cur = st & 1;
        const unsigned short* Sb = &Sb2[cur][0];
        const unsigned short* St = &St2[cur][0];

        bfrag a0 = *(const bfrag*)(Sb + (16 * w + x) * 64 + ((quad ^ mm) * 8));
        bfrag a1 = *(const bfrag*)(Sb + (16 * w + x) * 64 + (((quad + 4) ^ mm) * 8));
        #pragma unroll
        for (int nt = 0; nt < 4; nt++) {
            f32x4 acc = (f32x4){0.f, 0.f, 0.f, 0.f};
            acc = __builtin_amdgcn_mfma_f32_16x16x32_bf16(a0, fh[nt][0], acc, 0, 0, 0);
            acc = __builtin_amdgcn_mfma_f32_16x16x32_bf16(a1, fh[nt][1], acc, 0, 0, 0);
            acc = __builtin_amdgcn_mfma_f32_16x16x32_bf16(a0, fl[nt][0], acc, 0, 0, 0);
            acc = __builtin_amdgcn_mfma_f32_16x16x32_bf16(a1, fl[nt][1], acc, 0, 0, 0);
            float e0 = __expf(acc[0] - Mv[nt]);
            float e1 = __expf(acc[1] - Mv[nt]);
            float e2 = __expf(acc[2] - Mv[nt]);
            float e3 = __expf(acc[3] - Mv[nt]);
            zacc[nt] += (e0 + e1) + (e2 + e3);
            ushort4 ev;
            ev.x = f2bf(e0); ev.y = f2bf(e1); ev.z = f2bf(e2); ev.w = f2bf(e3);
            *(ushort4*)&Et[(nt * 16 + x) * 72 + 16 * w + quad * 4] = ev;
        }
        asm volatile("s_waitcnt lgkmcnt(0)" ::: "memory");
        asm volatile("s_barrier" ::: "memory");

        bfrag c0 = *(const bfrag*)(St + (16 * w + x) * 64 + ((quad ^ mm) * 8));
        bfrag c1 = *(const bfrag*)(St + (16 * w + x) * 64 + (((quad + 4) ^ mm) * 8));
        #pragma unroll
        for (int nt = 0; nt < 4; nt++) {
            bfrag e0 = *(const bfrag*)(Et + (nt * 16 + x) * 72 + quad * 8);
            bfrag e1 = *(const bfrag*)(Et + (nt * 16 + x) * 72 + 32 + quad * 8);
            Uacc[nt] = __builtin_amdgcn_mfma_f32_16x16x32_bf16(c0, e0, Uacc[nt], 0, 0, 0);
            Uacc[nt] = __builtin_amdgcn_mfma_f32_16x16x32_bf16(c1, e1, Uacc[nt], 0, 0, 0);
        }

        if (st < 6) {
            asm volatile("s_barrier" ::: "memory");
            stage(tile0 + st + 2, cur);
            asm volatile("s_waitcnt vmcnt(4)" ::: "memory");
            asm volatile("s_barrier" ::: "memory");
        } else if (st == 6) {
            asm volatile("s_waitcnt vmcnt(0)" ::: "memory");
            asm volatile("s_barrier" ::: "memory");
        }
    }

    // ---- U partials: private slice, plain stores (16-lane contiguous runs)
    float* Up = ws + UP_F;
    #pragma unroll
    for (int nt = 0; nt < 4; nt++) {
        #pragma unroll
        for (int r = 0; r < 4; r++) {
            int i = 16 * w + quad * 4 + r;
            Up[((btile * 64 + i) * 64 + chunk) * 64 + nt * 16 + x] = Uacc[nt][r];
        }
    }

    // ---- Z partials: quad shfl + cross-wave LDS reduce (reuse Et as scratch)
    __syncthreads();                       // all Et reads done
    float* zsh = (float*)Et;
    #pragma unroll
    for (int nt = 0; nt < 4; nt++) {
        float v = zacc[nt];
        v += __shfl_down(v, 32, 64);
        v += __shfl_down(v, 16, 64);
        if (quad == 0) zsh[w * 64 + nt * 16 + x] = v;
    }
    __syncthreads();
    if (t < 64) {
        float z = zsh[t] + zsh[64 + t] + zsh[128 + t] + zsh[192 + t];
        (ws + ZP_F)[(btile * 64 + chunk) * 64 + t] = z;
    }
    if (blockIdx.x == 0 && t == 0) out[0] = 0.f;   // precedes finalize (stream order)
}

// ---------------------------------------------------------------------------
// Finalize: sum 64 chunk-partials (coalesced stride-64 reads), p = U/Z,
// clamp, write out[1..]; masked BCE (log clamp -100), block reduce,
// atomicAdd loss into out[0] (128 block-level atomics only).
// Block = one label i (blockIdx>>1) x 256 consecutive b.
__global__ __launch_bounds__(256) void finalize_kernel(
    const float* __restrict__ ws, const float* __restrict__ y,
    const float* __restrict__ mask, float* __restrict__ out) {
    const int i     = blockIdx.x >> 1;
    const int b     = ((blockIdx.x & 1) << 8) + threadIdx.x;
    const int btile = b >> 6;
    const int bl    = b & 63;

    const float* zp = ws + ZP_F + (btile * 64) * 64 + bl;
    const float* up = ws + UP_F + ((btile * 64 + i) * 64) * 64 + bl;
    float z = 0.f, u = 0.f;
    #pragma unroll 8
    for (int c = 0; c < 64; c++) { z += zp[c * 64]; u += up[c * 64]; }

    float p = fminf(fmaxf(u / z, 0.f), 1.f);
    const int idx = b * 64 + i;
    out[1 + idx] = p;

    float lp  = fmaxf(logf(p), -100.f);
    float l1p = fmaxf(logf(1.f - p), -100.f);
    float yy = y[idx];
    float bce = -(yy * lp + (1.f - yy) * l1p) * mask[idx] * (1.f / (float)N_BATCH);

    float v = bce;
    #pragma unroll
    for (int off = 32; off > 0; off >>= 1) v += __shfl_down(v, off, 64);
    __shared__ float wsum[4];
    if ((threadIdx.x & 63) == 0) wsum[threadIdx.x >> 6] = v;
    __syncthreads();
    if (threadIdx.x == 0)
        atomicAdd(&out[0], wsum[0] + wsum[1] + wsum[2] + wsum[3]);
}

// ---------------------------------------------------------------------------
extern "C" void kernel_launch(void* const* d_in, const int* in_sizes, int n_in,
                              void* d_out, int out_size, void* d_ws, size_t ws_size,
                              hipStream_t stream) {
    const float* f    = (const float*)d_in[0];   // [512, 64]
    const float* S    = (const float*)d_in[1];   // [32768, 64]
    const float* y    = (const float*)d_in[2];   // [512, 64]
    const float* mask = (const float*)d_in[3];   // [512, 64]
    float* out = (float*)d_out;                  // [1 + 512*64]
    float* ws  = (float*)d_ws;

    prep_kernel<<<513, 256, 0, stream>>>(f, S, ws);
    fused_kernel<<<512, 256, 0, stream>>>(f, ws, out);
    finalize_kernel<<<128, 256, 0, stream>>>(ws, y, mask, out);
}

// Round 7
// 94.786 us; speedup vs baseline: 2.2622x; 1.0186x over previous
//
#include <hip/hip_runtime.h>
#include <hip/hip_bf16.h>
#include <math.h>

#define N_STATES 32768
#define N_LABELS 64
#define N_BATCH  512

// ws layout:
//   floats: Zp[8][64][64] @ ZP_F ; Up[8][64][64][64] @ UP_F
//   bytes : Sb (bf16, chunk-swizzled) @ SB_BYTE ; STb @ STB_BYTE
#define ZP_F     1024
#define UP_F     65536
#define SB_BYTE  8650752u
#define STB_BYTE 12845056u

typedef __attribute__((ext_vector_type(8))) short          bfrag;
typedef __attribute__((ext_vector_type(4))) short          bhalf;   // b64 LDS read
typedef __attribute__((ext_vector_type(4))) float          f32x4;
typedef __attribute__((ext_vector_type(8))) unsigned short u16x8;

static __device__ __forceinline__ unsigned short f2bf(float x) {
    __hip_bfloat16 h = __float2bfloat16(x);
    return *reinterpret_cast<unsigned short*>(&h);
}
static __device__ __forceinline__ float bf2f(unsigned short u) {
    __hip_bfloat16 h;
    *reinterpret_cast<unsigned short*>(&h) = u;
    return __bfloat162float(h);
}

typedef __attribute__((address_space(1))) const unsigned char g_u8;
typedef __attribute__((address_space(3))) unsigned char       l_u8;
static __device__ __forceinline__ void dma16(const void* g, void* l) {
    __builtin_amdgcn_global_load_lds((g_u8*)g, (l_u8*)l, 16, 0, 0);
}

// ---------------------------------------------------------------------------
// Prep: 512 blocks convert S tile -> Sb (natural) + STb (transposed), bf16,
// chunk-swizzled (physical 16B chunk p = logical ^ (row&7): conflict-free
// ds reads AND verbatim global_load_lds). No service block (round 6: the
// 513th block was a scheduling straggler; M moved into fused).
__global__ __launch_bounds__(256) void prep_kernel(
    const float* __restrict__ S, float* __restrict__ ws) {
    const int tb = blockIdx.x;
    const int t  = threadIdx.x;

    __shared__ alignas(16) unsigned short Sl[64 * 72];

    unsigned short* SbW = (unsigned short*)((char*)ws + SB_BYTE);
    unsigned short* StW = (unsigned short*)((char*)ws + STB_BYTE);

    const int r = t >> 2;
    const int q = t & 3;
    const int m = r & 7;

    const float4* p4 = reinterpret_cast<const float4*>(
        S + ((size_t)(tb * 64 + r)) * N_LABELS + q * 16);
    float4 v0 = p4[0], v1 = p4[1], v2 = p4[2], v3 = p4[3];
    float vf[16] = {v0.x,v0.y,v0.z,v0.w, v1.x,v1.y,v1.z,v1.w,
                    v2.x,v2.y,v2.z,v2.w, v3.x,v3.y,v3.z,v3.w};
    u16x8 lo8, hi8;
    #pragma unroll
    for (int j = 0; j < 8; j++) { lo8[j] = f2bf(vf[j]); hi8[j] = f2bf(vf[8 + j]); }

    *(u16x8*)&Sl[r * 72 + q * 16]     = lo8;
    *(u16x8*)&Sl[r * 72 + q * 16 + 8] = hi8;

    {
        unsigned short* dst = SbW + (size_t)tb * 4096 + r * 64 + (((2 * q) ^ (m & 6)) * 8);
        if (m & 1) { *(u16x8*)dst = hi8; *(u16x8*)(dst + 8) = lo8; }
        else       { *(u16x8*)dst = lo8; *(u16x8*)(dst + 8) = hi8; }
    }
    __syncthreads();

    const int i  = r;
    const int mi = i & 7;
    u16x8 tlo, thi;
    #pragma unroll
    for (int j = 0; j < 8; j++) {
        tlo[j] = Sl[(16 * q + j)     * 72 + i];
        thi[j] = Sl[(16 * q + 8 + j) * 72 + i];
    }
    {
        unsigned short* dst = StW + (size_t)tb * 4096 + i * 64 + (((2 * q) ^ (mi & 6)) * 8);
        if (mi & 1) { *(u16x8*)dst = thi; *(u16x8*)(dst + 8) = tlo; }
        else        { *(u16x8*)dst = tlo; *(u16x8*)(dst + 8) = thi; }
    }
}

// ---------------------------------------------------------------------------
// Fused GEMM1 + exp + GEMM2, E NEVER LEAVES REGISTERS.
// Key identity: GEMM1's C-frag (lane q,x holds E(s=16w+4q+r, b=nt*16+x)) is
// exactly the K=32 B-frag with k=8q+j -> s=16w+4q+j for j<4 (j>=4 zeroed, and
// the A half-frag zeroed to match) -- so GEMM2 consumes E in place. Each wave
// accumulates a full 64x64 U partial over its 16-state slice (64 VGPRs),
// merged once per block through LDS. Per tile: 2 ds_read_b128 + 4 ds_read_b64,
// 2 barriers, no lgkm drains. Grid 512 XCD-affine (chunk%8 -> XCD).
__global__ __launch_bounds__(256, 2) void fused_kernel(
    const float* __restrict__ f, float* __restrict__ ws,
    float* __restrict__ out) {
    // smem: [0,32768) = 2x(Sb tile 8K + St tile 8K) dbuf; epilogue overlays
    // [0,65536) as merge[4][4096] floats; [65536,66560) = zsh
    __shared__ alignas(16) unsigned char smem[66560];

    const char* SbG = (const char*)ws + SB_BYTE;
    const char* StG = (const char*)ws + STB_BYTE;

    const int t     = threadIdx.x;
    const int lane  = t & 63;
    const int w     = t >> 6;
    const int x     = lane & 15;
    const int quad  = lane >> 4;
    const int mm    = x & 7;
    const int btile = blockIdx.x >> 6;
    const int chunk = blockIdx.x & 63;
    const int tile0 = chunk * 8;

    // ---- f B-frags (hi/lo bf16 split ~ fp32) + M[b] via quad butterfly
    bfrag fh[4][2], fl[4][2];
    float Mv[4];
    #pragma unroll
    for (int nt = 0; nt < 4; nt++) {
        const float4* fp = reinterpret_cast<const float4*>(
            f + ((size_t)(btile * 64 + nt * 16 + x)) * N_LABELS);
        float msum = 0.f;
        #pragma unroll
        for (int kh = 0; kh < 2; kh++) {
            float4 a = fp[kh * 8 + quad * 2];
            float4 b = fp[kh * 8 + quad * 2 + 1];
            float vv[8] = {a.x,a.y,a.z,a.w, b.x,b.y,b.z,b.w};
            #pragma unroll
            for (int j = 0; j < 8; j++) {
                msum += fmaxf(vv[j], 0.f);
                unsigned short h = f2bf(vv[j]);
                fh[nt][kh][j] = (short)h;
                fl[nt][kh][j] = (short)f2bf(vv[j] - bf2f(h));
            }
        }
        // sum the 4 quad-partials (cols {8q..8q+7} u {32+8q..+7}) -> full row
        msum += __shfl_xor(msum, 16, 64);
        msum += __shfl_xor(msum, 32, 64);
        Mv[nt] = msum;   // sum_i max(f,0) >= any subset sum = pot bound
    }

    f32x4 Uacc[16];   // [it*4+nt]: U(i=it*16+4q+r, b=nt*16+x), wave's s-slice
    #pragma unroll
    for (int e = 0; e < 16; e++) Uacc[e] = (f32x4){0.f, 0.f, 0.f, 0.f};
    float zacc[4] = {0.f, 0.f, 0.f, 0.f};

    auto stage = [&](int tile, int buf) {
        size_t gb = (size_t)tile * 8192 + (size_t)w * 2048 + (size_t)lane * 16;
        int lo = w * 2048;
        dma16(SbG + gb,        smem + buf * 8192 + lo);
        dma16(SbG + gb + 1024, smem + buf * 8192 + lo + 1024);
        dma16(StG + gb,        smem + 16384 + buf * 8192 + lo);
        dma16(StG + gb + 1024, smem + 16384 + buf * 8192 + lo + 1024);
    };

    stage(tile0 + 0, 0);
    stage(tile0 + 1, 1);
    asm volatile("s_waitcnt vmcnt(4)" ::: "memory");
    asm volatile("s_barrier" ::: "memory");

    #pragma unroll
    for (int st = 0; st < 8; st++) {
        const int cur = st & 1;
        const unsigned short* Sb = (const unsigned short*)(smem + cur * 8192);
        const unsigned short* St = (const unsigned short*)(smem + 16384 + cur * 8192);

        // GEMM1 A-frags: Sb row 16w+x (wave's s-slice), swizzled chunks
        bfrag a0 = *(const bfrag*)(Sb + (16 * w + x) * 64 + ((quad ^ mm) * 8));
        bfrag a1 = *(const bfrag*)(Sb + (16 * w + x) * 64 + (((quad + 4) ^ mm) * 8));

        // GEMM2 A-frags: ST[i=it*16+x][s=16w+4q+j], j<4 in low b64, high zeroed
        bfrag A8[4];
        #pragma unroll
        for (int it = 0; it < 4; it++) {
            bhalf a4 = *(const bhalf*)(St + (16 * it + x) * 64 +
                         (((2 * w + (quad >> 1)) ^ mm) * 8) + 4 * (quad & 1));
            bfrag tmp = {a4[0], a4[1], a4[2], a4[3], 0, 0, 0, 0};
            A8[it] = tmp;
        }

        #pragma unroll
        for (int nt = 0; nt < 4; nt++) {
            f32x4 acc = (f32x4){0.f, 0.f, 0.f, 0.f};
            acc = __builtin_amdgcn_mfma_f32_16x16x32_bf16(a0, fh[nt][0], acc, 0, 0, 0);
            acc = __builtin_amdgcn_mfma_f32_16x16x32_bf16(a1, fh[nt][1], acc, 0, 0, 0);
            acc = __builtin_amdgcn_mfma_f32_16x16x32_bf16(a0, fl[nt][0], acc, 0, 0, 0);
            acc = __builtin_amdgcn_mfma_f32_16x16x32_bf16(a1, fl[nt][1], acc, 0, 0, 0);
            float e0 = __expf(acc[0] - Mv[nt]);
            float e1 = __expf(acc[1] - Mv[nt]);
            float e2 = __expf(acc[2] - Mv[nt]);
            float e3 = __expf(acc[3] - Mv[nt]);
            zacc[nt] += (e0 + e1) + (e2 + e3);
            // E in-register as GEMM2 B-frag (k=8q+j -> s=16w+4q+j, j<4)
            bfrag Bf = {(short)f2bf(e0), (short)f2bf(e1),
                        (short)f2bf(e2), (short)f2bf(e3), 0, 0, 0, 0};
            #pragma unroll
            for (int it = 0; it < 4; it++)
                Uacc[it * 4 + nt] =
                    __builtin_amdgcn_mfma_f32_16x16x32_bf16(A8[it], Bf, Uacc[it * 4 + nt], 0, 0, 0);
        }

        if (st < 6) {
            asm volatile("s_barrier" ::: "memory");          // cur consumed
            stage(tile0 + st + 2, cur);
            asm volatile("s_waitcnt vmcnt(4)" ::: "memory"); // st+1 landed
            asm volatile("s_barrier" ::: "memory");
        } else if (st == 6) {
            asm volatile("s_waitcnt vmcnt(0)" ::: "memory");
            asm volatile("s_barrier" ::: "memory");
        }
    }

    // ---- merge the 4 wave partials through LDS (frag-order: conflict-free)
    __syncthreads();                        // all tile reads done; overlay bufs
    float* mg  = (float*)smem;              // [4][64 regs][64 lanes]
    float* zsh = (float*)(smem + 65536);
    #pragma unroll
    for (int e = 0; e < 16; e++) {
        #pragma unroll
        for (int r = 0; r < 4; r++)
            mg[w * 4096 + (e * 4 + r) * 64 + lane] = Uacc[e][r];
    }
    #pragma unroll
    for (int nt = 0; nt < 4; nt++) {
        float v = zacc[nt];
        v += __shfl_down(v, 32, 64);
        v += __shfl_down(v, 16, 64);
        if (quad == 0) zsh[w * 64 + nt * 16 + x] = v;
    }
    __syncthreads();

    float* Up = ws + UP_F;
    #pragma unroll
    for (int k = 0; k < 16; k++) {
        int idx = k * 256 + t;
        int e  = idx >> 6;                  // reg slot: ((it*4+nt)*4+r)
        int ln = idx & 63;
        int it = e >> 4, nt = (e >> 2) & 3, r = e & 3;
        int i  = it * 16 + (ln >> 4) * 4 + r;
        int b  = nt * 16 + (ln & 15);
        float s = mg[idx] + mg[4096 + idx] + mg[8192 + idx] + mg[12288 + idx];
        Up[((btile * 64 + i) * 64 + chunk) * 64 + b] = s;
    }
    if (t < 64) {
        float z = zsh[t] + zsh[64 + t] + zsh[128 + t] + zsh[192 + t];
        (ws + ZP_F)[(btile * 64 + chunk) * 64 + t] = z;
    }
    if (blockIdx.x == 0 && t == 0) out[0] = 0.f;   // before finalize (stream order)
}

// ---------------------------------------------------------------------------
// Finalize: sum 64 chunk-partials, p = U/Z, clamp, write out[1..]; masked BCE
// (log clamp -100), block reduce, atomicAdd loss into out[0].
__global__ __launch_bounds__(256) void finalize_kernel(
    const float* __restrict__ ws, const float* __restrict__ y,
    const float* __restrict__ mask, float* __restrict__ out) {
    const int i     = blockIdx.x >> 1;
    const int b     = ((blockIdx.x & 1) << 8) + threadIdx.x;
    const int btile = b >> 6;
    const int bl    = b & 63;

    const float* zp = ws + ZP_F + (btile * 64) * 64 + bl;
    const float* up = ws + UP_F + ((btile * 64 + i) * 64) * 64 + bl;
    float z = 0.f, u = 0.f;
    #pragma unroll 8
    for (int c = 0; c < 64; c++) { z += zp[c * 64]; u += up[c * 64]; }

    float p = fminf(fmaxf(u / z, 0.f), 1.f);
    const int idx = b * 64 + i;
    out[1 + idx] = p;

    float lp  = fmaxf(logf(p), -100.f);
    float l1p = fmaxf(logf(1.f - p), -100.f);
    float yy = y[idx];
    float bce = -(yy * lp + (1.f - yy) * l1p) * mask[idx] * (1.f / (float)N_BATCH);

    float v = bce;
    #pragma unroll
    for (int off = 32; off > 0; off >>= 1) v += __shfl_down(v, off, 64);
    __shared__ float wsum[4];
    if ((threadIdx.x & 63) == 0) wsum[threadIdx.x >> 6] = v;
    __syncthreads();
    if (threadIdx.x == 0)
        atomicAdd(&out[0], wsum[0] + wsum[1] + wsum[2] + wsum[3]);
}

// ---------------------------------------------------------------------------
extern "C" void kernel_launch(void* const* d_in, const int* in_sizes, int n_in,
                              void* d_out, int out_size, void* d_ws, size_t ws_size,
                              hipStream_t stream) {
    const float* f    = (const float*)d_in[0];   // [512, 64]
    const float* S    = (const float*)d_in[1];   // [32768, 64]
    const float* y    = (const float*)d_in[2];   // [512, 64]
    const float* mask = (const float*)d_in[3];   // [512, 64]
    float* out = (float*)d_out;                  // [1 + 512*64]
    float* ws  = (float*)d_ws;

    prep_kernel<<<512, 256, 0, stream>>>(S, ws);
    fused_kernel<<<512, 256, 0, stream>>>(f, ws, out);
    finalize_kernel<<<128, 256, 0, stream>>>(ws, y, mask, out);
}